// Round 8
// baseline (103.059 us; speedup 1.0000x reference)
//
#include <hip/hip_runtime.h>

#define B_SZ 256
#define C_SZ 1152
#define MO   128            // M*O = 8*16
#define CAPS_EPS 1e-8f

// uhat-fused-R0 geometry: 72 c-splits x 32 b-tiles; block = 16 c x 8 b.
#define USPL 72
#define UCPB 16             // c per uhat block
#define UCPW 4              // c per wave (4 waves)
#define UBPB 8              // b per uhat block
// route geometry: 32 c-splits x 32 b-tiles (8 b each), as in rounds 3-6.
#define CSPL 32
#define CRNG (C_SZ / CSPL)  // 36

struct alignas(8) H4 { _Float16 h[4]; };
union PK2 { unsigned int u32; _Float16 h[2]; };

// ---------------------------------------------------------------------------
// K1: u_hat (fp16) + fused R=0 partial sums.
// grid = USPL*32 (csp = bid>>5, bt = bid&31), block = 256 = 4 waves.
// Wave wv owns c's {c0 + wv*4 + k}; lane l owns mo rows 2l, 2l+1 (W in 16
// VGPRs via coalesced float4 loads, streamed per c). u[8b][16c][8] staged in
// 4 KB LDS once, read back as broadcast ds_read_b128 (round-6 win, no
// wave-uniform global loads). Each lane accumulates s0-partial for its
// (8 b x 2 mo) in regs; 16 KB LDS reduce across waves -> part0[csp][8b][128].
// ROUND-8 FIX: epilogue reduce now writes the FULL 128-mo row (float4 per
// thread; round 7 wrote only mo 0..63 -> half of part0 was ws poison).
__global__ __launch_bounds__(256, 4) void caps_uhat_f(
    const float* __restrict__ u,      // [B,C,8]
    const float* __restrict__ W,      // [C,128,8]
    unsigned int* __restrict__ uhat,  // [C,B,64] dwords (= [C,B,128] fp16)
    float* __restrict__ part0)        // [USPL,B,128]
{
    const int bid = blockIdx.x;
    const int csp = bid >> 5;
    const int bt  = bid & 31;
    const int c0  = csp * UCPB;
    const int b0  = bt * UBPB;
    const int tid = threadIdx.x;
    const int l   = tid & 63;
    const int wv  = tid >> 6;

    __shared__ __align__(16) float u_sh[UBPB][UCPB][8];     // 4 KB
    __shared__ __align__(16) float s_lds[4][UBPB][MO];      // 16 KB

    // stage u[b0:b0+8][c0:c0+16][0:8] (one-time, semi-coalesced)
    if (tid < 128) {
        const int bb = tid >> 4, cl = tid & 15;
        const float4* up = reinterpret_cast<const float4*>(
            u + ((size_t)(b0 + bb) * C_SZ + c0 + cl) * 8);
        *reinterpret_cast<float4*>(&u_sh[bb][cl][0]) = up[0];
        *reinterpret_cast<float4*>(&u_sh[bb][cl][4]) = up[1];
    }
    __syncthreads();

    float acc[UBPB][2];
#pragma unroll
    for (int bb = 0; bb < UBPB; ++bb) { acc[bb][0] = 0.f; acc[bb][1] = 0.f; }

#pragma unroll
    for (int k = 0; k < UCPW; ++k) {
        const int cl = wv * UCPW + k;
        const int c  = c0 + cl;
        // W[c] rows mo=2l (wa,wb) and mo=2l+1 (wc4,wd): coalesced float4
        const float4* wp =
            reinterpret_cast<const float4*>(W + (size_t)c * 1024) + l * 4;
        const float4 wa = wp[0], wb = wp[1], wc4 = wp[2], wd = wp[3];

        unsigned int* ub = uhat + (size_t)c * B_SZ * 64 + l;
#pragma unroll
        for (int bb = 0; bb < UBPB; ++bb) {
            const float4 u0 =
                *reinterpret_cast<const float4*>(&u_sh[bb][cl][0]);
            const float4 u1 =
                *reinterpret_cast<const float4*>(&u_sh[bb][cl][4]);
            float h0 = wa.x*u0.x + wa.y*u0.y + wa.z*u0.z + wa.w*u0.w
                     + wb.x*u1.x + wb.y*u1.y + wb.z*u1.z + wb.w*u1.w;
            float h1 = wc4.x*u0.x + wc4.y*u0.y + wc4.z*u0.z + wc4.w*u0.w
                     + wd.x*u1.x + wd.y*u1.y + wd.z*u1.z + wd.w*u1.w;
            PK2 pk;
            pk.h[0] = (_Float16)h0;
            pk.h[1] = (_Float16)h1;
            ub[(size_t)(b0 + bb) * 64] = pk.u32;  // 256B/wave coalesced
            acc[bb][0] += h0;
            acc[bb][1] += h1;
        }
    }

    // cross-wave reduce of R0 partials (weight 1/8 uniform)
#pragma unroll
    for (int bb = 0; bb < UBPB; ++bb)
        *reinterpret_cast<float2*>(&s_lds[wv][bb][2 * l]) =
            make_float2(acc[bb][0] * 0.125f, acc[bb][1] * 0.125f);
    __syncthreads();

    {
        // 8 b x 32 threads x float4 = full 128-mo row per b  (round-8 fix)
        const int bb = tid >> 5, j = tid & 31;
        float4 r = make_float4(0.f, 0.f, 0.f, 0.f);
#pragma unroll
        for (int w = 0; w < 4; ++w) {
            const float4 x =
                *reinterpret_cast<const float4*>(&s_lds[w][bb][4 * j]);
            r.x += x.x; r.y += x.y; r.z += x.z; r.w += x.w;
        }
        *reinterpret_cast<float4*>(
            part0 + ((size_t)csp * B_SZ + b0 + bb) * MO + 4 * j) = r;
    }
}

// ---------------------------------------------------------------------------
// vcalc: vout = squash(sum_{k<nsplit} part_in[k]) (+ addv if non-null).
// grid = B, block = 128.
__global__ __launch_bounds__(128) void caps_vcalc(
    const float* __restrict__ part_in,  // [nsplit,B,128]
    const float* __restrict__ addv,     // [B,128] or null
    float* __restrict__ vout,           // [B,128]
    int nsplit)
{
    const int b = blockIdx.x, t = threadIdx.x;
    float s = 0.f;
    for (int k = 0; k < nsplit; ++k)
        s += part_in[((size_t)k * B_SZ + b) * MO + t];
    float n2 = s * s;                   // 16-lane group = one m row
    n2 += __shfl_xor(n2, 1);
    n2 += __shfl_xor(n2, 2);
    n2 += __shfl_xor(n2, 4);
    n2 += __shfl_xor(n2, 8);
    float norm = sqrtf(n2);
    float v = (n2 / (1.f + n2)) * s / (norm + CAPS_EPS);
    if (addv) v += addv[(size_t)b * MO + t];
    vout[(size_t)b * MO + t] = v;
}

// ---------------------------------------------------------------------------
// route: one routing pass over materialized u_hat (softmax weights from v).
__global__ __launch_bounds__(256) void caps_route(
    const H4* __restrict__ uhat,        // [C,B,32]
    const float* __restrict__ vbuf,     // [B,128]
    float* __restrict__ part_out)       // [CSPL,B,128]
{
    const int bt  = blockIdx.x & 31;
    const int csp = blockIdx.x >> 5;
    const int tid = threadIdx.x;
    const int g   = tid >> 5;
    const int l   = tid & 31;
    const int b   = bt * 8 + g;
    const int mo4 = l * 4;

    const float4 v4 =
        *reinterpret_cast<const float4*>(vbuf + (size_t)b * MO + mo4);
    float acc[4] = {0.f, 0.f, 0.f, 0.f};

    const int cbeg = csp * CRNG, cend = cbeg + CRNG;
    const H4* base = uhat + (size_t)b * 32 + l;  // stride B_SZ*32 per c

    H4 r0 = base[(size_t)cbeg * B_SZ * 32];
    H4 r1 = base[(size_t)(cbeg + 1) * B_SZ * 32];

    for (int c = cbeg; c < cend; c += 2) {
        H4 n0 = r0, n1 = r1;
        if (c + 2 < cend) {
            n0 = base[(size_t)(c + 2) * B_SZ * 32];
            n1 = base[(size_t)(c + 3) * B_SZ * 32];
        }
#pragma unroll
        for (int q = 0; q < 2; ++q) {
            H4 r = q ? r1 : r0;
            float uh0 = (float)r.h[0], uh1 = (float)r.h[1];
            float uh2 = (float)r.h[2], uh3 = (float)r.h[3];
            float uv = uh0 * v4.x + uh1 * v4.y + uh2 * v4.z + uh3 * v4.w;
            uv += __shfl_xor(uv, 1);      // reduce over o-quarters
            uv += __shfl_xor(uv, 2);      // -> uv[m] on 4 lanes
            float mx = fmaxf(uv, __shfl_xor(uv, 4));
            mx = fmaxf(mx, __shfl_xor(mx, 8));
            mx = fmaxf(mx, __shfl_xor(mx, 16));
            float e = expf(uv - mx);
            float den = e;
            den += __shfl_xor(den, 4);
            den += __shfl_xor(den, 8);
            den += __shfl_xor(den, 16);
            float cw = e / den;
            acc[0] = fmaf(cw, uh0, acc[0]);
            acc[1] = fmaf(cw, uh1, acc[1]);
            acc[2] = fmaf(cw, uh2, acc[2]);
            acc[3] = fmaf(cw, uh3, acc[3]);
        }
        r0 = n0; r1 = n1;
    }
    *reinterpret_cast<float4*>(part_out + ((size_t)csp * B_SZ + b) * MO + mo4) =
        make_float4(acc[0], acc[1], acc[2], acc[3]);
}

// ---------------------------------------------------------------------------
// Fallback (small-ws): round-1 fused kernel, needs only 384 KB of ws.
template <int R>
__global__ __launch_bounds__(256) void caps_small(
    const float* __restrict__ u, const float* __restrict__ W,
    const float* __restrict__ s_in, const float* __restrict__ v0_in,
    float* __restrict__ s_out, float* __restrict__ v0_out,
    float* __restrict__ out)
{
    const int b = blockIdx.x, tid = threadIdx.x;
    __shared__ float sh_v[8][17];
    __shared__ float sh_part[256][17];

    if (R >= 1) {
        if (tid < 128) {
            float val = s_in[b * 128 + tid];
            float n2 = val * val;
            n2 += __shfl_xor(n2, 1); n2 += __shfl_xor(n2, 2);
            n2 += __shfl_xor(n2, 4); n2 += __shfl_xor(n2, 8);
            float norm = sqrtf(n2);
            float v = (n2 / (1.f + n2)) * val / (norm + CAPS_EPS);
            int m = tid >> 4, o = tid & 15;
            if (R == 1) { v0_out[b * 128 + tid] = v; sh_v[m][o] = v; }
            else        { sh_v[m][o] = v + v0_in[b * 128 + tid]; }
        }
        __syncthreads();
    }
    const int c_local = tid >> 3, m = tid & 7;
    float s_acc[16];
#pragma unroll
    for (int o = 0; o < 16; ++o) s_acc[o] = 0.f;
    for (int cc = 0; cc < C_SZ; cc += 32) {
        const int c = cc + c_local;
        const float4* up = reinterpret_cast<const float4*>(
            u + (size_t)(b * C_SZ + c) * 8);
        float4 u0 = up[0], u1 = up[1];
        float u8[8] = {u0.x, u0.y, u0.z, u0.w, u1.x, u1.y, u1.z, u1.w};
        float uh[16];
        const float4* wp = reinterpret_cast<const float4*>(
            W + (size_t)((c * 8 + m) * 16) * 8);
#pragma unroll
        for (int o = 0; o < 16; ++o) {
            float4 w0 = wp[o * 2], w1 = wp[o * 2 + 1];
            uh[o] = w0.x * u8[0] + w0.y * u8[1] + w0.z * u8[2] + w0.w * u8[3] +
                    w1.x * u8[4] + w1.y * u8[5] + w1.z * u8[6] + w1.w * u8[7];
        }
        float cw;
        if (R == 0) cw = 0.125f;
        else {
            float uv = 0.f;
#pragma unroll
            for (int o = 0; o < 16; ++o) uv = fmaf(uh[o], sh_v[m][o], uv);
            float mx = uv;
            mx = fmaxf(mx, __shfl_xor(mx, 1));
            mx = fmaxf(mx, __shfl_xor(mx, 2));
            mx = fmaxf(mx, __shfl_xor(mx, 4));
            float e = expf(uv - mx);
            float den = e;
            den += __shfl_xor(den, 1); den += __shfl_xor(den, 2);
            den += __shfl_xor(den, 4);
            cw = e / den;
        }
#pragma unroll
        for (int o = 0; o < 16; ++o) s_acc[o] = fmaf(cw, uh[o], s_acc[o]);
    }
#pragma unroll
    for (int o = 0; o < 16; ++o) sh_part[tid][o] = s_acc[o];
    __syncthreads();
    if (tid < 128) {
        const int m2 = tid >> 4, o2 = tid & 15;
        float s = 0.f;
#pragma unroll
        for (int gg = 0; gg < 32; ++gg) s += sh_part[gg * 8 + m2][o2];
        if (R < 2) s_out[b * 128 + tid] = s;
        else {
            float n2 = s * s;
            n2 += __shfl_xor(n2, 1); n2 += __shfl_xor(n2, 2);
            n2 += __shfl_xor(n2, 4); n2 += __shfl_xor(n2, 8);
            float norm = sqrtf(n2);
            out[b * 128 + tid] = (n2 / (1.f + n2)) * s / (norm + CAPS_EPS);
        }
    }
}

extern "C" void kernel_launch(void* const* d_in, const int* in_sizes, int n_in,
                              void* d_out, int out_size, void* d_ws, size_t ws_size,
                              hipStream_t stream) {
    const float* u = (const float*)d_in[0];  // [256,1152,8]
    const float* W = (const float*)d_in[1];  // [1152,8,16,8]
    float* out = (float*)d_out;              // [256,8,16]

    const size_t UHAT_BYTES = (size_t)C_SZ * B_SZ * MO * 2;      // 75.5 MB
    const size_t P0_FLOATS  = (size_t)USPL * B_SZ * MO;          // 9.4 MB
    const size_t PR_FLOATS  = (size_t)CSPL * B_SZ * MO;          // 4.2 MB
    const size_t NEED = UHAT_BYTES +
                        (P0_FLOATS + 2 * PR_FLOATS + 2 * B_SZ * MO) * 4;

    if (ws_size >= NEED) {
        unsigned int* uhat_w = (unsigned int*)d_ws;
        const H4* uhat_r = (const H4*)d_ws;
        float* part0 = (float*)((char*)d_ws + UHAT_BYTES);
        float* partA = part0 + P0_FLOATS;
        float* partB = partA + PR_FLOATS;
        float* v0    = partB + PR_FLOATS;
        float* vsum  = v0 + B_SZ * MO;

        dim3 blk(256);
        caps_uhat_f<<<dim3(USPL * 32), blk, 0, stream>>>(u, W, uhat_w, part0);
        caps_vcalc<<<dim3(B_SZ), dim3(128), 0, stream>>>(part0, nullptr, v0, USPL);
        caps_route<<<dim3(CSPL * 32), blk, 0, stream>>>(uhat_r, v0, partA);
        caps_vcalc<<<dim3(B_SZ), dim3(128), 0, stream>>>(partA, v0, vsum, CSPL);
        caps_route<<<dim3(CSPL * 32), blk, 0, stream>>>(uhat_r, vsum, partB);
        caps_vcalc<<<dim3(B_SZ), dim3(128), 0, stream>>>(partB, nullptr, out, CSPL);
    } else {
        // small-ws fallback (round-1 path)
        float* sA = (float*)d_ws;
        float* sB = sA + 32768;
        float* v0 = sB + 32768;
        dim3 grid(B_SZ), blk(256);
        caps_small<0><<<grid, blk, 0, stream>>>(u, W, nullptr, nullptr, sA, nullptr, nullptr);
        caps_small<1><<<grid, blk, 0, stream>>>(u, W, sA, nullptr, sB, v0, nullptr);
        caps_small<2><<<grid, blk, 0, stream>>>(u, W, sB, v0, nullptr, nullptr, out);
    }
}